// Round 7
// baseline (521.166 us; speedup 1.0000x reference)
//
#include <hip/hip_runtime.h>

// RewardTripletLoss — R6. R5's tail_kernel was 420us: u64 LDS atomicAdd is NOT
// a single native ds_add (dependent ~250cyc RMW chains) and the loss branch's
// pk[8] cache pushed VGPR to 84 (achieved occupancy 31% -> no latency hiding).
// Fix: revert to R2-proven u32 ds_add_u32 dual histograms (h_pos updated only
// for the rare pos elems), pack (Hp<<32|Ha) AFTER atomics for the exact scan;
// loss branch re-reads global instead of caching (VGPR diet).
// Structure: 2 launches. A: fused cvt+GEMM (32x32x2). B: loss+fastap+final
// (last-block atomic-counter protocol, validated in R5).

#define N_ROWS 4096
#define DIM 128
#define TILE 128
#define L_BINS 1601

typedef __bf16 bf16x8 __attribute__((ext_vector_type(8)));
typedef float f32x4 __attribute__((ext_vector_type(4)));

__device__ __forceinline__ unsigned short f32_to_bf16(float f) {
    unsigned int u = __float_as_uint(f);
    u = (u + 0x7FFFu + ((u >> 16) & 1u)) >> 16;
    return (unsigned short)u;
}
__device__ __forceinline__ unsigned int pack2(float x, float y) {
    return (unsigned int)f32_to_bf16(x) | ((unsigned int)f32_to_bf16(y) << 16);
}
__device__ __forceinline__ float bf16_lo(unsigned int u) { return __uint_as_float(u << 16); }
__device__ __forceinline__ float bf16_hi(unsigned int u) { return __uint_as_float(u & 0xFFFF0000u); }

__device__ __forceinline__ void unpack8(uint4 pk, float* s) {
    s[0] = bf16_lo(pk.x); s[1] = bf16_hi(pk.x);
    s[2] = bf16_lo(pk.y); s[3] = bf16_hi(pk.y);
    s[4] = bf16_lo(pk.z); s[5] = bf16_hi(pk.z);
    s[6] = bf16_lo(pk.w); s[7] = bf16_hi(pk.w);
}

// ---------------- Kernel A: fused cvt + GEMM ----------------
__global__ __launch_bounds__(256) void gemm_kernel(
    const float* __restrict__ incol, const float* __restrict__ inrow,
    unsigned short* __restrict__ simbuf, unsigned short* __restrict__ grambuf) {
    __shared__ __align__(16) unsigned short As[TILE * DIM];  // 32 KB bf16
    __shared__ __align__(16) unsigned short Bs[TILE * DIM];  // 32 KB bf16
    int t = threadIdx.x;
    int w = t >> 6, lane = t & 63;
    int tm = blockIdx.y, tn = blockIdx.x;
    const float* ga = incol + (size_t)tm * TILE * DIM;  // tile contiguous: 64 KB f32
    const float* gb = (blockIdx.z ? incol : inrow) + (size_t)tn * TILE * DIM;
    unsigned short* C = blockIdx.z ? grambuf : simbuf;

#pragma unroll
    for (int it = 0; it < 8; ++it) {
        int fo = it * 2048 + t * 8;
        float4 a0 = *(const float4*)(ga + fo);
        float4 a1 = *(const float4*)(ga + fo + 4);
        float4 b0 = *(const float4*)(gb + fo);
        float4 b1 = *(const float4*)(gb + fo + 4);
        uint4 pa, pb;
        pa.x = pack2(a0.x, a0.y); pa.y = pack2(a0.z, a0.w);
        pa.z = pack2(a1.x, a1.y); pa.w = pack2(a1.z, a1.w);
        pb.x = pack2(b0.x, b0.y); pb.y = pack2(b0.z, b0.w);
        pb.z = pack2(b1.x, b1.y); pb.w = pack2(b1.z, b1.w);
        *(uint4*)((char*)As + it * 4096 + t * 16) = pa;
        *(uint4*)((char*)Bs + it * 4096 + t * 16) = pb;
    }
    __syncthreads();

    int wm = (w & 1) * 64;
    int wn = (w >> 1) * 64;
    int quad = lane >> 4;
    int l15 = lane & 15;
    f32x4 acc[4][4] = {};
#pragma unroll
    for (int kk = 0; kk < 4; ++kk) {
        int kb = kk * 32 + quad * 8;
        bf16x8 af[4], bfr[4];
#pragma unroll
        for (int mi = 0; mi < 4; ++mi)
            af[mi] = *(const bf16x8*)&As[(wm + mi * 16 + l15) * DIM + kb];
#pragma unroll
        for (int ni = 0; ni < 4; ++ni)
            bfr[ni] = *(const bf16x8*)&Bs[(wn + ni * 16 + l15) * DIM + kb];
#pragma unroll
        for (int mi = 0; mi < 4; ++mi)
#pragma unroll
            for (int ni = 0; ni < 4; ++ni)
                acc[mi][ni] = __builtin_amdgcn_mfma_f32_16x16x32_bf16(af[mi], bfr[ni], acc[mi][ni], 0, 0, 0);
    }
#pragma unroll
    for (int mi = 0; mi < 4; ++mi) {
        int row0 = tm * TILE + wm + mi * 16 + quad * 4;
#pragma unroll
        for (int ni = 0; ni < 4; ++ni) {
            int col = tn * TILE + wn + ni * 16 + l15;
#pragma unroll
            for (int r = 0; r < 4; ++r)
                C[(size_t)(row0 + r) * N_ROWS + col] = f32_to_bf16(acc[mi][ni][r]);
        }
    }
}

// ---------------- Kernel B: loss + fastap + last-block final ----------------
__global__ __launch_bounds__(256) void tail_kernel(
    const unsigned short* __restrict__ simbuf, const unsigned short* __restrict__ grambuf,
    const int* __restrict__ tcol, const int* __restrict__ trow, const int* __restrict__ rlab,
    float* __restrict__ lossv, float* __restrict__ rewardv,
    unsigned int* __restrict__ counter, float* __restrict__ out) {
    __shared__ unsigned int h_pos[L_BINS];   // 6.4 KB
    __shared__ unsigned int h_all[L_BINS];   // 6.4 KB
    __shared__ unsigned long long wsumA[4];
    __shared__ float apwA[4];
    __shared__ int npwA[4];
    __shared__ unsigned int sdone;
    int b = blockIdx.x;
    int t = threadIdx.x;
    int w = t >> 6, lane = t & 63;

    if (b < 1024) {
        // ---- triplet loss, one wave per row; two global passes (row is L2-hot) ----
        int i = b * 4 + w;
        int myt = tcol[i];
        const uint4* simv = (const uint4*)(simbuf + (size_t)i * N_ROWS);
        const int4* labv = (const int4*)trow;
        float pmax = -3e38f, nmax = -3e38f;
#pragma unroll
        for (int v = 0; v < 8; ++v) {
            int vi = v * 64 + lane;
            uint4 pk = simv[vi];
            int4 l0 = labv[2 * vi];
            int4 l1 = labv[2 * vi + 1];
            int j0 = vi * 8;
            float s[8];
            unpack8(pk, s);
            int lab[8] = {l0.x, l0.y, l0.z, l0.w, l1.x, l1.y, l1.z, l1.w};
#pragma unroll
            for (int k = 0; k < 8; ++k) {
                int j = j0 + k;
                bool same = (lab[k] == myt);
                if (same && (j != i)) pmax = fmaxf(pmax, s[k]);
                if (!same) nmax = fmaxf(nmax, s[k]);
            }
        }
#pragma unroll
        for (int off = 32; off > 0; off >>= 1) {
            pmax = fmaxf(pmax, __shfl_xor(pmax, off));
            nmax = fmaxf(nmax, __shfl_xor(nmax, off));
        }
        float thr_n = nmax + 0.1f;
        float thr_p = fmaxf(0.6f, pmax) - 0.1f;
        float pl = 0.f, nl = 0.f;
#pragma unroll
        for (int v = 0; v < 8; ++v) {
            int vi = v * 64 + lane;
            uint4 pk = simv[vi];
            int4 l0 = labv[2 * vi];
            int4 l1 = labv[2 * vi + 1];
            int j0 = vi * 8;
            float s[8];
            unpack8(pk, s);
            int lab[8] = {l0.x, l0.y, l0.z, l0.w, l1.x, l1.y, l1.z, l1.w};
#pragma unroll
            for (int k = 0; k < 8; ++k) {
                int j = j0 + k;
                bool same = (lab[k] == myt);
                pl += (same && (j != i) && s[k] < thr_n) ? 1.f - s[k] : 0.f;
                nl += (!same && s[k] > thr_p) ? s[k] : 0.f;
            }
        }
        float tot = pl + nl;
#pragma unroll
        for (int off = 32; off > 0; off >>= 1) tot += __shfl_xor(tot, off);
        if (lane == 0) lossv[i] = (pmax > -1e30f) ? tot : 0.f;
    } else {
        // ---- FastAP, one row per block; u32 native ds_add histograms ----
        int i = b - 1024;
        for (int bb = t; bb < L_BINS; bb += 256) { h_pos[bb] = 0u; h_all[bb] = 0u; }
        __syncthreads();
        int li = rlab[i];
        int npos = 0;
        const uint4* gv = (const uint4*)(grambuf + (size_t)i * N_ROWS);
        const int4* labv = (const int4*)rlab;
        for (int v = t; v < (N_ROWS >> 3); v += 256) {
            uint4 pk = gv[v];
            int4 l0 = labv[2 * v];
            int4 l1 = labv[2 * v + 1];
            int j0 = v << 3;
            float s[8];
            unpack8(pk, s);
            int lab[8] = {l0.x, l0.y, l0.z, l0.w, l1.x, l1.y, l1.z, l1.w};
#pragma unroll
            for (int k = 0; k < 8; ++k) {
                int j = j0 + k;
                if (j == i) continue;
                float d2 = fminf(fmaxf(2.f - 2.f * s[k], 0.f), 4.f);
                float tt = d2 * 400.0f;
                float fl = floorf(tt);
                int i0 = (int)fl;
                if (i0 > L_BINS - 1) i0 = L_BINS - 1;
                int i1 = i0 + 1;
                if (i1 > L_BINS - 1) i1 = L_BINS - 1;
                unsigned int w1 = (unsigned int)((tt - fl) * 65536.0f);
                unsigned int w0 = 65536u - w1;
                atomicAdd(&h_all[i0], w0);
                atomicAdd(&h_all[i1], w1);
                if (lab[k] == li) {  // rare (~npos/n): extra 2 atomics only here
                    atomicAdd(&h_pos[i0], w0);
                    atomicAdd(&h_pos[i1], w1);
                    npos++;
                }
            }
        }
        __syncthreads();

        // Exact scan: pack (pos<<32 | all) in registers, shfl-scan (no atomics).
        const int CH = 7;  // 256*7 = 1792 >= 1601
        int base = t * CH;
        unsigned long long lc[CH];
        unsigned long long run = 0ull;
#pragma unroll
        for (int k = 0; k < CH; ++k) {
            int idx = base + k;
            unsigned long long h = 0ull;
            if (idx < L_BINS)
                h = (unsigned long long)h_all[idx] | ((unsigned long long)h_pos[idx] << 32);
            run += h;
            lc[k] = run;
        }
        unsigned long long tsum = run;
        unsigned long long sc = tsum;
#pragma unroll
        for (int off = 1; off < 64; off <<= 1) {
            unsigned long long v2 = __shfl_up(sc, off);
            if (lane >= off) sc += v2;
        }
        if (lane == 63) wsumA[w] = sc;
        __syncthreads();
        unsigned long long woff = 0ull;
        for (int ww = 0; ww < w; ++ww) woff += wsumA[ww];
        unsigned long long throff = woff + sc - tsum;

        float ap = 0.f;
#pragma unroll
        for (int k = 0; k < CH; ++k) {
            int idx = base + k;
            if (idx < L_BINS) {
                unsigned int hp = h_pos[idx];
                if (hp) {
                    unsigned long long cum = lc[k] + throff;
                    ap += (float)hp * (float)(unsigned int)(cum >> 32) / (float)(unsigned int)cum;
                }
            }
        }
#pragma unroll
        for (int off = 32; off > 0; off >>= 1) {
            ap += __shfl_xor(ap, off);
            npos += __shfl_xor(npos, off);
        }
        if (lane == 0) { apwA[w] = ap; npwA[w] = npos; }
        __syncthreads();
        if (t == 0) {
            float A = apwA[0] + apwA[1] + apwA[2] + apwA[3];
            int np = npwA[0] + npwA[1] + npwA[2] + npwA[3];
            rewardv[i] = (np > 0) ? A * (1.0f / 65536.0f) / (float)np : 0.f;
        }
    }

    // ---- completion protocol: last finishing block computes the final scalar ----
    __threadfence();
    __syncthreads();
    if (t == 0) sdone = atomicAdd(counter, 1u);
    __syncthreads();
    if (sdone == gridDim.x - 1) {
        __threadfence();
        float s = 0.f;
        for (int j = t; j < N_ROWS; j += 256) {
            float lv = __hip_atomic_load(&lossv[j], __ATOMIC_RELAXED, __HIP_MEMORY_SCOPE_AGENT);
            float rv = __hip_atomic_load(&rewardv[j], __ATOMIC_RELAXED, __HIP_MEMORY_SCOPE_AGENT);
            s += lv * (1.f - rv);
        }
#pragma unroll
        for (int off = 32; off > 0; off >>= 1) s += __shfl_xor(s, off);
        if (lane == 0) apwA[w] = s;
        __syncthreads();
        if (t == 0) out[0] = (apwA[0] + apwA[1] + apwA[2] + apwA[3]) / (float)N_ROWS;
    }
}

extern "C" void kernel_launch(void* const* d_in, const int* in_sizes, int n_in,
                              void* d_out, int out_size, void* d_ws, size_t ws_size,
                              hipStream_t stream) {
    const float* inputs_col = (const float*)d_in[0];
    const int* targets_col = (const int*)d_in[1];
    const float* inputs_row = (const float*)d_in[2];
    const int* targets_row = (const int*)d_in[3];
    const int* reward_labels = (const int*)d_in[4];
    float* out = (float*)d_out;

    char* ws = (char*)d_ws;
    const size_t MB = 1048576;
    unsigned short* simbuf = (unsigned short*)ws;                 // 32 MB
    unsigned short* grambuf = (unsigned short*)(ws + 32 * MB);    // 32 MB
    float* lossv = (float*)(ws + 64 * MB);                        // 16 KB
    float* rewardv = (float*)(ws + 64 * MB + 16384);              // 16 KB
    unsigned int* counter = (unsigned int*)(ws + 64 * MB + 32768);

    hipMemsetAsync(counter, 0, 4, stream);  // graph-capture-legal

    dim3 ggrid(N_ROWS / TILE, N_ROWS / TILE, 2);
    gemm_kernel<<<ggrid, 256, 0, stream>>>(inputs_col, inputs_row, simbuf, grambuf);

    tail_kernel<<<1024 + N_ROWS, 256, 0, stream>>>(simbuf, grambuf,
                                                   targets_col, targets_row, reward_labels,
                                                   lossv, rewardv, counter, out);
}

// Round 8
// 143.114 us; speedup vs baseline: 3.6416x; 3.6416x over previous
//
#include <hip/hip_runtime.h>

// RewardTripletLoss — R7. R6 falsified the "u64 atomic" theory: u32 revert
// halved SQ_LDS_BANK_CONFLICT but dur unchanged (420->428us). The shared
// culprit in R5/R6 is the per-block completion protocol: 5120 device-scope
// __threadfence (L2 writeback on non-coherent-XCD gfx950) + serialized
// cross-XCD atomicAdd on ONE counter line. Removed; final reduce is its own
// tiny launch (kernel boundary = one flush total, not 5120).
// 3 launches: A fused cvt+GEMM (32x32x2) / B loss+fastap / C final.

#define N_ROWS 4096
#define DIM 128
#define TILE 128
#define L_BINS 1601

typedef __bf16 bf16x8 __attribute__((ext_vector_type(8)));
typedef float f32x4 __attribute__((ext_vector_type(4)));

__device__ __forceinline__ unsigned short f32_to_bf16(float f) {
    unsigned int u = __float_as_uint(f);
    u = (u + 0x7FFFu + ((u >> 16) & 1u)) >> 16;
    return (unsigned short)u;
}
__device__ __forceinline__ unsigned int pack2(float x, float y) {
    return (unsigned int)f32_to_bf16(x) | ((unsigned int)f32_to_bf16(y) << 16);
}
__device__ __forceinline__ float bf16_lo(unsigned int u) { return __uint_as_float(u << 16); }
__device__ __forceinline__ float bf16_hi(unsigned int u) { return __uint_as_float(u & 0xFFFF0000u); }

__device__ __forceinline__ void unpack8(uint4 pk, float* s) {
    s[0] = bf16_lo(pk.x); s[1] = bf16_hi(pk.x);
    s[2] = bf16_lo(pk.y); s[3] = bf16_hi(pk.y);
    s[4] = bf16_lo(pk.z); s[5] = bf16_hi(pk.z);
    s[6] = bf16_lo(pk.w); s[7] = bf16_hi(pk.w);
}

// ---------------- Kernel A: fused cvt + GEMM ----------------
__global__ __launch_bounds__(256) void gemm_kernel(
    const float* __restrict__ incol, const float* __restrict__ inrow,
    unsigned short* __restrict__ simbuf, unsigned short* __restrict__ grambuf) {
    __shared__ __align__(16) unsigned short As[TILE * DIM];  // 32 KB bf16
    __shared__ __align__(16) unsigned short Bs[TILE * DIM];  // 32 KB bf16
    int t = threadIdx.x;
    int w = t >> 6, lane = t & 63;
    int tm = blockIdx.y, tn = blockIdx.x;
    const float* ga = incol + (size_t)tm * TILE * DIM;  // tile contiguous: 64 KB f32
    const float* gb = (blockIdx.z ? incol : inrow) + (size_t)tn * TILE * DIM;
    unsigned short* C = blockIdx.z ? grambuf : simbuf;

#pragma unroll
    for (int it = 0; it < 8; ++it) {
        int fo = it * 2048 + t * 8;
        float4 a0 = *(const float4*)(ga + fo);
        float4 a1 = *(const float4*)(ga + fo + 4);
        float4 b0 = *(const float4*)(gb + fo);
        float4 b1 = *(const float4*)(gb + fo + 4);
        uint4 pa, pb;
        pa.x = pack2(a0.x, a0.y); pa.y = pack2(a0.z, a0.w);
        pa.z = pack2(a1.x, a1.y); pa.w = pack2(a1.z, a1.w);
        pb.x = pack2(b0.x, b0.y); pb.y = pack2(b0.z, b0.w);
        pb.z = pack2(b1.x, b1.y); pb.w = pack2(b1.z, b1.w);
        *(uint4*)((char*)As + it * 4096 + t * 16) = pa;
        *(uint4*)((char*)Bs + it * 4096 + t * 16) = pb;
    }
    __syncthreads();

    int wm = (w & 1) * 64;
    int wn = (w >> 1) * 64;
    int quad = lane >> 4;
    int l15 = lane & 15;
    f32x4 acc[4][4] = {};
#pragma unroll
    for (int kk = 0; kk < 4; ++kk) {
        int kb = kk * 32 + quad * 8;
        bf16x8 af[4], bfr[4];
#pragma unroll
        for (int mi = 0; mi < 4; ++mi)
            af[mi] = *(const bf16x8*)&As[(wm + mi * 16 + l15) * DIM + kb];
#pragma unroll
        for (int ni = 0; ni < 4; ++ni)
            bfr[ni] = *(const bf16x8*)&Bs[(wn + ni * 16 + l15) * DIM + kb];
#pragma unroll
        for (int mi = 0; mi < 4; ++mi)
#pragma unroll
            for (int ni = 0; ni < 4; ++ni)
                acc[mi][ni] = __builtin_amdgcn_mfma_f32_16x16x32_bf16(af[mi], bfr[ni], acc[mi][ni], 0, 0, 0);
    }
#pragma unroll
    for (int mi = 0; mi < 4; ++mi) {
        int row0 = tm * TILE + wm + mi * 16 + quad * 4;
#pragma unroll
        for (int ni = 0; ni < 4; ++ni) {
            int col = tn * TILE + wn + ni * 16 + l15;
#pragma unroll
            for (int r = 0; r < 4; ++r)
                C[(size_t)(row0 + r) * N_ROWS + col] = f32_to_bf16(acc[mi][ni][r]);
        }
    }
}

// ---------------- Kernel B: loss (blocks 0..1023) + fastap (1024..5119) ----------------
__global__ __launch_bounds__(256) void tail_kernel(
    const unsigned short* __restrict__ simbuf, const unsigned short* __restrict__ grambuf,
    const int* __restrict__ tcol, const int* __restrict__ trow, const int* __restrict__ rlab,
    float* __restrict__ lossv, float* __restrict__ rewardv) {
    __shared__ unsigned int h_pos[L_BINS];   // 6.4 KB
    __shared__ unsigned int h_all[L_BINS];   // 6.4 KB
    __shared__ unsigned long long wsumA[4];
    __shared__ float apwA[4];
    __shared__ int npwA[4];
    int b = blockIdx.x;
    int t = threadIdx.x;
    int w = t >> 6, lane = t & 63;

    if (b < 1024) {
        // ---- triplet loss, one wave per row; two global passes (row is L2-hot) ----
        int i = b * 4 + w;
        int myt = tcol[i];
        const uint4* simv = (const uint4*)(simbuf + (size_t)i * N_ROWS);
        const int4* labv = (const int4*)trow;
        float pmax = -3e38f, nmax = -3e38f;
#pragma unroll
        for (int v = 0; v < 8; ++v) {
            int vi = v * 64 + lane;
            uint4 pk = simv[vi];
            int4 l0 = labv[2 * vi];
            int4 l1 = labv[2 * vi + 1];
            int j0 = vi * 8;
            float s[8];
            unpack8(pk, s);
            int lab[8] = {l0.x, l0.y, l0.z, l0.w, l1.x, l1.y, l1.z, l1.w};
#pragma unroll
            for (int k = 0; k < 8; ++k) {
                int j = j0 + k;
                bool same = (lab[k] == myt);
                if (same && (j != i)) pmax = fmaxf(pmax, s[k]);
                if (!same) nmax = fmaxf(nmax, s[k]);
            }
        }
#pragma unroll
        for (int off = 32; off > 0; off >>= 1) {
            pmax = fmaxf(pmax, __shfl_xor(pmax, off));
            nmax = fmaxf(nmax, __shfl_xor(nmax, off));
        }
        float thr_n = nmax + 0.1f;
        float thr_p = fmaxf(0.6f, pmax) - 0.1f;
        float pl = 0.f, nl = 0.f;
#pragma unroll
        for (int v = 0; v < 8; ++v) {
            int vi = v * 64 + lane;
            uint4 pk = simv[vi];
            int4 l0 = labv[2 * vi];
            int4 l1 = labv[2 * vi + 1];
            int j0 = vi * 8;
            float s[8];
            unpack8(pk, s);
            int lab[8] = {l0.x, l0.y, l0.z, l0.w, l1.x, l1.y, l1.z, l1.w};
#pragma unroll
            for (int k = 0; k < 8; ++k) {
                int j = j0 + k;
                bool same = (lab[k] == myt);
                pl += (same && (j != i) && s[k] < thr_n) ? 1.f - s[k] : 0.f;
                nl += (!same && s[k] > thr_p) ? s[k] : 0.f;
            }
        }
        float tot = pl + nl;
#pragma unroll
        for (int off = 32; off > 0; off >>= 1) tot += __shfl_xor(tot, off);
        if (lane == 0) lossv[i] = (pmax > -1e30f) ? tot : 0.f;
    } else {
        // ---- FastAP, one row per block; u32 native ds_add histograms ----
        int i = b - 1024;
        for (int bb = t; bb < L_BINS; bb += 256) { h_pos[bb] = 0u; h_all[bb] = 0u; }
        __syncthreads();
        int li = rlab[i];
        int npos = 0;
        const uint4* gv = (const uint4*)(grambuf + (size_t)i * N_ROWS);
        const int4* labv = (const int4*)rlab;
        for (int v = t; v < (N_ROWS >> 3); v += 256) {
            uint4 pk = gv[v];
            int4 l0 = labv[2 * v];
            int4 l1 = labv[2 * v + 1];
            int j0 = v << 3;
            float s[8];
            unpack8(pk, s);
            int lab[8] = {l0.x, l0.y, l0.z, l0.w, l1.x, l1.y, l1.z, l1.w};
#pragma unroll
            for (int k = 0; k < 8; ++k) {
                int j = j0 + k;
                if (j == i) continue;
                float d2 = fminf(fmaxf(2.f - 2.f * s[k], 0.f), 4.f);
                float tt = d2 * 400.0f;
                float fl = floorf(tt);
                int i0 = (int)fl;
                if (i0 > L_BINS - 1) i0 = L_BINS - 1;
                int i1 = i0 + 1;
                if (i1 > L_BINS - 1) i1 = L_BINS - 1;
                unsigned int w1 = (unsigned int)((tt - fl) * 65536.0f);
                unsigned int w0 = 65536u - w1;
                atomicAdd(&h_all[i0], w0);
                atomicAdd(&h_all[i1], w1);
                if (lab[k] == li) {  // rare (~npos/n): extra atomics only here
                    atomicAdd(&h_pos[i0], w0);
                    atomicAdd(&h_pos[i1], w1);
                    npos++;
                }
            }
        }
        __syncthreads();

        // Exact scan: pack (pos<<32 | all) in registers, shfl-scan (no atomics).
        const int CH = 7;  // 256*7 = 1792 >= 1601
        int base = t * CH;
        unsigned long long lc[CH];
        unsigned long long run = 0ull;
#pragma unroll
        for (int k = 0; k < CH; ++k) {
            int idx = base + k;
            unsigned long long h = 0ull;
            if (idx < L_BINS)
                h = (unsigned long long)h_all[idx] | ((unsigned long long)h_pos[idx] << 32);
            run += h;
            lc[k] = run;
        }
        unsigned long long tsum = run;
        unsigned long long sc = tsum;
#pragma unroll
        for (int off = 1; off < 64; off <<= 1) {
            unsigned long long v2 = __shfl_up(sc, off);
            if (lane >= off) sc += v2;
        }
        if (lane == 63) wsumA[w] = sc;
        __syncthreads();
        unsigned long long woff = 0ull;
        for (int ww = 0; ww < w; ++ww) woff += wsumA[ww];
        unsigned long long throff = woff + sc - tsum;

        float ap = 0.f;
#pragma unroll
        for (int k = 0; k < CH; ++k) {
            int idx = base + k;
            if (idx < L_BINS) {
                unsigned int hp = h_pos[idx];
                if (hp) {
                    unsigned long long cum = lc[k] + throff;
                    ap += (float)hp * (float)(unsigned int)(cum >> 32) / (float)(unsigned int)cum;
                }
            }
        }
#pragma unroll
        for (int off = 32; off > 0; off >>= 1) {
            ap += __shfl_xor(ap, off);
            npos += __shfl_xor(npos, off);
        }
        if (lane == 0) { apwA[w] = ap; npwA[w] = npos; }
        __syncthreads();
        if (t == 0) {
            float A = apwA[0] + apwA[1] + apwA[2] + apwA[3];
            int np = npwA[0] + npwA[1] + npwA[2] + npwA[3];
            rewardv[i] = (np > 0) ? A * (1.0f / 65536.0f) / (float)np : 0.f;
        }
    }
}

// ---------------- Kernel C: final scalar ----------------
__global__ __launch_bounds__(256) void final_kernel(const float* __restrict__ lossv,
                                                    const float* __restrict__ rewardv,
                                                    float* __restrict__ out) {
    __shared__ float r[4];
    int t = threadIdx.x;
    int w = t >> 6, lane = t & 63;
    float s = 0.f;
    for (int j = t; j < N_ROWS; j += 256) s += lossv[j] * (1.f - rewardv[j]);
#pragma unroll
    for (int off = 32; off > 0; off >>= 1) s += __shfl_xor(s, off);
    if (lane == 0) r[w] = s;
    __syncthreads();
    if (t == 0) out[0] = (r[0] + r[1] + r[2] + r[3]) / (float)N_ROWS;
}

extern "C" void kernel_launch(void* const* d_in, const int* in_sizes, int n_in,
                              void* d_out, int out_size, void* d_ws, size_t ws_size,
                              hipStream_t stream) {
    const float* inputs_col = (const float*)d_in[0];
    const int* targets_col = (const int*)d_in[1];
    const float* inputs_row = (const float*)d_in[2];
    const int* targets_row = (const int*)d_in[3];
    const int* reward_labels = (const int*)d_in[4];
    float* out = (float*)d_out;

    char* ws = (char*)d_ws;
    const size_t MB = 1048576;
    unsigned short* simbuf = (unsigned short*)ws;                 // 32 MB
    unsigned short* grambuf = (unsigned short*)(ws + 32 * MB);    // 32 MB
    float* lossv = (float*)(ws + 64 * MB);                        // 16 KB
    float* rewardv = (float*)(ws + 64 * MB + 16384);              // 16 KB

    dim3 ggrid(N_ROWS / TILE, N_ROWS / TILE, 2);
    gemm_kernel<<<ggrid, 256, 0, stream>>>(inputs_col, inputs_row, simbuf, grambuf);

    tail_kernel<<<1024 + N_ROWS, 256, 0, stream>>>(simbuf, grambuf,
                                                   targets_col, targets_row, reward_labels,
                                                   lossv, rewardv);

    final_kernel<<<1, 256, 0, stream>>>(lossv, rewardv, out);
}